// Round 1
// baseline (190.396 us; speedup 1.0000x reference)
//
#include <hip/hip_runtime.h>
#include <hip/hip_bf16.h>

// TAttention: B=16, C=32, N=1024, T=128, R=10
//  k[b,n,t]   = sum_c alpha[c] * x[b,c,n,t]
//  kw1[b,t,r] = sum_n k[b,n,t] * W1[r,n]   (same for kw2/W2)
//  scores[b,t,s] = sum_r kw1[t,r]*kw2[s,r]; att = softmax_s
//  out[b,c,n,t] = sum_s att[b,t,s] * x[b,c,n,s]   <- MFMA bf16, memory-bound

#define B_ 16
#define C_ 32
#define N_ 1024
#define T_ 128
#define R_ 10
#define CH_ 16          // n-chunks for kw partials
#define NCH_ (N_ / CH_) // 64 n per chunk

typedef __bf16 bf16x8 __attribute__((ext_vector_type(8)));
typedef __bf16 bf16x4 __attribute__((ext_vector_type(4)));
typedef float f32x4 __attribute__((ext_vector_type(4)));

// ---------------------------------------------------------------- kernel 1
// k[b][n][t] = sum_c alpha[c] * x[b][c][n][t]; float4 over t, coalesced.
__global__ __launch_bounds__(256) void k_reduce_c(const float* __restrict__ x,
                                                  const float* __restrict__ alpha,
                                                  float* __restrict__ k) {
    int bid = blockIdx.x;            // B * N/8 = 2048
    int b   = bid >> 7;
    int nc  = bid & 127;
    int tid = threadIdx.x;
    int nl  = tid >> 5;              // 0..7
    int lc  = tid & 31;              // 32 lanes * float4 = 128 t
    int n   = nc * 8 + nl;
    const float4* xb = reinterpret_cast<const float4*>(
        x + ((size_t)(b * C_) * N_ + n) * T_) + lc;
    float4 acc = {0.f, 0.f, 0.f, 0.f};
    #pragma unroll 8
    for (int c = 0; c < C_; ++c) {
        float a = alpha[c];
        float4 v = xb[(size_t)c * (N_ * T_ / 4)];
        acc.x += a * v.x; acc.y += a * v.y; acc.z += a * v.z; acc.w += a * v.w;
    }
    reinterpret_cast<float4*>(k + ((size_t)b * N_ + n) * T_)[lc] = acc;
}

// ---------------------------------------------------------------- kernel 2
// per n-chunk partial kw: p1[b][ch][t][r] = sum_{n in chunk} k[b,n,t]*W1[r,n]
__global__ __launch_bounds__(128) void kw_partial(const float* __restrict__ k,
                                                  const float* __restrict__ W1,
                                                  const float* __restrict__ W2,
                                                  float* __restrict__ p1,
                                                  float* __restrict__ p2) {
    __shared__ __align__(16) float ws[NCH_][20];   // [n_local][r: 10 W1 | 10 W2]
    int bid = blockIdx.x;    // B * CH_
    int b   = bid >> 4;
    int ch  = bid & (CH_ - 1);
    int n0  = ch * NCH_;
    int t   = threadIdx.x;
    for (int i = t; i < NCH_ * R_; i += 128) {
        int r = i / NCH_, nl = i % NCH_;
        ws[nl][r]      = W1[r * N_ + n0 + nl];
        ws[nl][R_ + r] = W2[r * N_ + n0 + nl];
    }
    __syncthreads();
    float a1[R_] = {}, a2[R_] = {};
    const float* kb = k + ((size_t)b * N_ + n0) * T_ + t;
    for (int nl = 0; nl < NCH_; ++nl) {
        float kv = kb[nl * T_];
        float wv[20];
        const float4* wr = reinterpret_cast<const float4*>(&ws[nl][0]);
        #pragma unroll
        for (int q = 0; q < 5; ++q) *reinterpret_cast<float4*>(&wv[q * 4]) = wr[q];
        #pragma unroll
        for (int r = 0; r < R_; ++r) {
            a1[r] += kv * wv[r];
            a2[r] += kv * wv[R_ + r];
        }
    }
    size_t o = ((size_t)(b * CH_ + ch) * T_ + t) * R_;
    #pragma unroll
    for (int r = 0; r < R_; ++r) { p1[o + r] = a1[r]; p2[o + r] = a2[r]; }
}

// ---------------------------------------------------------------- kernel 3
// reduce partials, scores, softmax (f32), write att as bf16 [b][t][s]
__global__ __launch_bounds__(128) void scores_softmax(const float* __restrict__ p1,
                                                      const float* __restrict__ p2,
                                                      __bf16* __restrict__ att) {
    __shared__ __align__(16) float kw1s[T_][12];
    __shared__ __align__(16) float kw2s[T_][12];
    __shared__ float sc[T_][T_ + 1];
    int b = blockIdx.x;
    int t = threadIdx.x;
    #pragma unroll
    for (int r = 0; r < R_; ++r) {
        float s1 = 0.f, s2 = 0.f;
        for (int ch = 0; ch < CH_; ++ch) {
            size_t o = ((size_t)(b * CH_ + ch) * T_ + t) * R_ + r;
            s1 += p1[o]; s2 += p2[o];
        }
        kw1s[t][r] = s1; kw2s[t][r] = s2;
    }
    __syncthreads();
    float myw[R_];
    #pragma unroll
    for (int r = 0; r < R_; ++r) myw[r] = kw1s[t][r];
    float mx = -1e30f;
    for (int s = 0; s < T_; ++s) {
        float wv[12];
        const float4* qr = reinterpret_cast<const float4*>(&kw2s[s][0]);
        #pragma unroll
        for (int q = 0; q < 3; ++q) *reinterpret_cast<float4*>(&wv[q * 4]) = qr[q];
        float v = 0.f;
        #pragma unroll
        for (int r = 0; r < R_; ++r) v += myw[r] * wv[r];
        sc[t][s] = v;
        mx = fmaxf(mx, v);
    }
    float sum = 0.f;
    for (int s = 0; s < T_; ++s) {
        float e = __expf(sc[t][s] - mx);
        sc[t][s] = e;
        sum += e;
    }
    float inv = 1.0f / sum;
    for (int s = 0; s < T_; ++s) sc[t][s] *= inv;
    __syncthreads();
    // coalesced bf16 store: att[b][i][t]
    for (int i = 0; i < T_; ++i)
        att[((size_t)b * T_ + i) * T_ + t] = (__bf16)sc[i][t];
}

// ---------------------------------------------------------------- kernel 4
// out[n,t] = sum_s x[n,s]*att[t,s] per (b,c) slab; MFMA 16x16x32 bf16.
__global__ __launch_bounds__(256) void out_gemm(const float* __restrict__ x,
                                                const __bf16* __restrict__ att,
                                                float* __restrict__ out) {
    __shared__ __align__(16) __bf16 attl[T_][136]; // rows stride 272B (pad: 2-way alias, free)
    __shared__ __align__(16) __bf16 xsl[64][136];
    int bid = blockIdx.x;          // B*C*(N/64) = 8192
    int nc  = bid & 15;
    int c   = (bid >> 4) & 31;
    int b   = bid >> 9;
    int tid = threadIdx.x;
    size_t slab = ((size_t)(b * C_ + c) * N_ + nc * 64) * T_;

    // stage att[b] (bf16, 32KB) -> LDS
    const uint4* ga = reinterpret_cast<const uint4*>(att + (size_t)b * T_ * T_);
    #pragma unroll
    for (int i = 0; i < 8; ++i) {
        int e = i * 256 + tid;         // uint4 = 8 bf16
        int el = e * 8;
        *reinterpret_cast<uint4*>(&attl[el >> 7][el & 127]) = ga[e];
    }
    // stage x slab (f32 32KB) -> bf16 LDS
    const float4* gx = reinterpret_cast<const float4*>(x + slab);
    #pragma unroll
    for (int i = 0; i < 8; ++i) {
        int e = i * 256 + tid;
        int el = e * 4;
        float4 v = gx[e];
        bf16x4 h = {(__bf16)v.x, (__bf16)v.y, (__bf16)v.z, (__bf16)v.w};
        *reinterpret_cast<bf16x4*>(&xsl[el >> 7][el & 127]) = h;
    }
    __syncthreads();

    int w = tid >> 6, lane = tid & 63;
    int r16 = lane & 15, g = lane >> 4;
    f32x4 acc[8] = {};
    #pragma unroll
    for (int ks = 0; ks < 4; ++ks) {
        bf16x8 af = *reinterpret_cast<const bf16x8*>(&xsl[w * 16 + r16][ks * 32 + g * 8]);
        #pragma unroll
        for (int tt = 0; tt < 8; ++tt) {
            bf16x8 bfr = *reinterpret_cast<const bf16x8*>(&attl[tt * 16 + r16][ks * 32 + g * 8]);
            acc[tt] = __builtin_amdgcn_mfma_f32_16x16x32_bf16(af, bfr, acc[tt], 0, 0, 0);
        }
    }
    // C/D layout (HW-verified): col = lane&15, row = (lane>>4)*4 + j
    float* o = out + slab;
    #pragma unroll
    for (int tt = 0; tt < 8; ++tt) {
        #pragma unroll
        for (int j = 0; j < 4; ++j)
            o[(size_t)(w * 16 + g * 4 + j) * T_ + tt * 16 + r16] = acc[tt][j];
    }
}

// ----------------------------------------------------------------
extern "C" void kernel_launch(void* const* d_in, const int* in_sizes, int n_in,
                              void* d_out, int out_size, void* d_ws, size_t ws_size,
                              hipStream_t stream) {
    const float* x     = (const float*)d_in[0];
    const float* W1    = (const float*)d_in[1];
    const float* W2    = (const float*)d_in[2];
    const float* alpha = (const float*)d_in[3];
    float* out = (float*)d_out;

    float* k  = (float*)d_ws;                           // 16*1024*128 f32 = 8 MB
    float* p1 = k + (size_t)B_ * N_ * T_;               // 16*16*128*10 f32
    float* p2 = p1 + (size_t)B_ * CH_ * T_ * R_;
    __bf16* att = (__bf16*)(p2 + (size_t)B_ * CH_ * T_ * R_);  // 16*128*128 bf16

    k_reduce_c<<<dim3(B_ * (N_ / 8)), dim3(256), 0, stream>>>(x, alpha, k);
    kw_partial<<<dim3(B_ * CH_), dim3(128), 0, stream>>>(k, W1, W2, p1, p2);
    scores_softmax<<<dim3(B_), dim3(128), 0, stream>>>(p1, p2, att);
    out_gemm<<<dim3(B_ * C_ * (N_ / 64)), dim3(256), 0, stream>>>(x, att, out);
}